// Round 1
// baseline (283.194 us; speedup 1.0000x reference)
//
#include <hip/hip_runtime.h>
#include <math.h>

#define B_DIM 4
#define C_DIM 256
#define N_DIM 2048
#define H_DIM 8
#define HD    64
#define HB    32                 // H*B
#define NTOK  (B_DIM * N_DIM)    // 8192
#define LOG2E 1.44269504f

typedef __attribute__((ext_vector_type(8))) short bf16x8;
typedef __attribute__((ext_vector_type(4))) float f32x4;

static __device__ __forceinline__ short f2bf(float f) {          // RNE (cold paths)
    unsigned u = __builtin_bit_cast(unsigned, f);
    u += 0x7fffu + ((u >> 16) & 1u);
    return (short)(u >> 16);
}
static __device__ __forceinline__ float bf2f(short s) {
    unsigned u = ((unsigned)(unsigned short)s) << 16;
    return __builtin_bit_cast(float, u);
}
// raw v_exp_f32: exact for |x| <~ 126, skips OCML's range-guard sequence
static __device__ __forceinline__ float fx2(float x) {
#if __has_builtin(__builtin_amdgcn_exp2f)
    return __builtin_amdgcn_exp2f(x);
#else
    return exp2f(x);
#endif
}
// pack two fp32 -> two bf16 in one dword (HW packed cvt when available)
static __device__ __forceinline__ unsigned pk_bf16(float a, float b) {
#if __has_builtin(__builtin_amdgcn_cvt_pk_bf16_f32)
    auto v = __builtin_amdgcn_cvt_pk_bf16_f32(a, b);
    return __builtin_bit_cast(unsigned, v);
#else
    unsigned ua = __builtin_bit_cast(unsigned, a);
    unsigned ub = __builtin_bit_cast(unsigned, b);
    return ((ua + 0x8000u) >> 16) | ((ub + 0x8000u) & 0xffff0000u);
#endif
}

#define MFMA16(A, Bv, Cv) __builtin_amdgcn_mfma_f32_16x16x32_bf16(A, Bv, Cv, 0, 0, 0)

// Fragment-major layouts (fragment = 64 lanes x 16 B = 1 KB contiguous):
//   QS/KS(hb, rt, ks, lane, j) = M[hb][n = rt*16 + (lane&15)][d = ks*32 + (lane>>4)*8 + j]
//   (QS holds Q * log2e so exp() becomes exp2())
//   VS(hb, nb, ks, dt, lane, j) = V[hb][d = dt*16+(lane&15)][n = nb*64+ks*32+(lane>>4)*8+j]
//   XS/YS(rt, ks, lane, j) = X[tok = rt*16+(lane&15)][c = ks*32+(lane>>4)*8+j]
//   WS(ot, ks, lane, j)    = W[o  = ot*16+(lane&15)][c = ks*32+(lane>>4)*8+j]

// ---------------------------------------------------------------------------
// cast+transpose to fragment-major (z 0..7: x/y batches) + weights (z == 8)
// ---------------------------------------------------------------------------
__global__ __launch_bounds__(256) void cast_all(
    const float* __restrict__ X, const float* __restrict__ Y,
    const float* __restrict__ Wq, const float* __restrict__ Wk,
    const float* __restrict__ Wv, const float* __restrict__ Wp,
    short* __restrict__ XS, short* __restrict__ YS,
    short* __restrict__ WSx, short* __restrict__ WSy)
{
    const int z = blockIdx.z;
    const int t = threadIdx.x;

    if (z == 8) {   // ---- weights: Wq -> WSx (256 chunks); Wk|Wv|Wp -> WSy (544) ----
        int base = (blockIdx.y * 32 + blockIdx.x) * 256 + t;   // 0..32767
#pragma unroll
        for (int rep = 0; rep < 2; ++rep) {
            int gid = base + rep * 32768;                       // 0..65535
            if (gid >= 51200) break;
            int lane = gid & 63, chunk = gid >> 6;              // chunk 0..799
            int lo = lane & 15, quad = lane >> 4;
            const float* src; short* dst;
            if (chunk < 256) {
                int ot = chunk >> 3, ks = chunk & 7;
                src = Wq + (size_t)(ot * 16 + lo) * C_DIM + ks * 32 + quad * 8;
                dst = WSx + (size_t)chunk * 512 + lane * 8;
            } else {
                int ch = chunk - 256;
                int ot = ch >> 3, ks = ch & 7;
                int row = ot * 16 + lo;
                const float* basep = (row < 512) ? (Wk + (size_t)row * C_DIM)
                                   : (row < 1024) ? (Wv + (size_t)(row - 512) * C_DIM)
                                                  : (Wp + (size_t)(row - 1024) * C_DIM);
                src = basep + ks * 32 + quad * 8;
                dst = WSy + (size_t)ch * 512 + lane * 8;
            }
            bf16x8 o;
#pragma unroll
            for (int j = 0; j < 8; ++j) o[j] = f2bf(src[j]);
            *(bf16x8*)dst = o;
        }
        return;
    }

    const float* src = (z < 4) ? X : Y;
    short* dst = (z < 4) ? XS : YS;
    const int b = z & 3, c0 = blockIdx.y * 64, n0 = blockIdx.x * 64;
    __shared__ float L[64][65];   // [c_local][n_local]
    for (int i = t; i < 4096; i += 256) {
        int cc = i >> 6, nn = i & 63;
        L[cc][nn] = src[((size_t)b * C_DIM + c0 + cc) * N_DIM + n0 + nn];
    }
    __syncthreads();
#pragma unroll
    for (int half = 0; half < 2; ++half) {
        int cid = half * 256 + t;
        int lane = cid & 63, fi = cid >> 6;      // fi 0..7
        int ksl = fi & 1, rtl = fi >> 1;         // rtl 0..3
        int lo = lane & 15, quad = lane >> 4;
        bf16x8 o;
#pragma unroll
        for (int j = 0; j < 8; ++j) o[j] = f2bf(L[ksl * 32 + quad * 8 + j][rtl * 16 + lo]);
        int rt = b * 128 + (n0 >> 4) + rtl;
        int ks = (c0 >> 5) + ksl;
        *(bf16x8*)(dst + ((size_t)(rt * 8 + ks) * 64 + lane) * 8) = o;
    }
}

// ---------------------------------------------------------------------------
// Merged MFMA projection, all loads coalesced fragment loads.
// oy<8: Q=(Wq x + bq)*log2e -> QS. oy 8..15: K -> KS. oy 16..23: V -> VSu.
// oy==24: YP fp32 (b,n,d). Epilogue: LDS transpose -> coalesced 16B stores.
// ---------------------------------------------------------------------------
__global__ __launch_bounds__(256) void proj_all(
    const short* __restrict__ WSx, const short* __restrict__ WSy,
    const short* __restrict__ XS, const short* __restrict__ YS,
    const float* __restrict__ bq, const float* __restrict__ bk,
    const float* __restrict__ bv,
    short* __restrict__ QS, short* __restrict__ KS,
    short* __restrict__ VSu, float* __restrict__ Yo)
{
    const int oy = blockIdx.y;
    const bool isq = oy < 8;
    const short* WS = isq ? WSx : WSy;
    const short* Xs = isq ? XS : YS;
    const int oyl = isq ? oy : oy - 8;
    const int o0 = oyl * 64;
    const int tok0 = blockIdx.x * 128;
    const int t = threadIdx.x, wave = t >> 6, lane = t & 63;
    const int lo = lane & 15, quad = lane >> 4;

    __shared__ __align__(16) char smem[34816];

    const int ot = oyl * 4 + wave;
    const int rt0 = tok0 >> 4;
    const f32x4 czero = {0.f, 0.f, 0.f, 0.f};

    f32x4 acc[8];
#pragma unroll
    for (int i = 0; i < 8; ++i) acc[i] = czero;

#pragma unroll 2
    for (int ks = 0; ks < 8; ++ks) {
        bf16x8 a = *(const bf16x8*)(WS + ((size_t)(ot * 8 + ks) * 64 + lane) * 8);
#pragma unroll
        for (int nt = 0; nt < 8; ++nt) {
            bf16x8 bx = *(const bf16x8*)(Xs + ((size_t)((rt0 + nt) * 8 + ks) * 64 + lane) * 8);
            acc[nt] = MFMA16(a, bx, acc[nt]);
        }
    }

    const int b = tok0 >> 11;
    const int n0b = tok0 & (N_DIM - 1);

    if (oy < 16) {
        // ---- Q or K: T[128][72] bf16 -> fragment-major QS/KS ----
        short* T = (short*)smem;
        const float* bias = isq ? bq : bk;
        const float scale = isq ? LOG2E : 1.f;
        float bvr[4];
#pragma unroll
        for (int r = 0; r < 4; ++r) bvr[r] = bias[o0 + wave * 16 + quad * 4 + r];
#pragma unroll
        for (int nt = 0; nt < 8; ++nt) {
            short4 pk;
            pk.x = f2bf((acc[nt][0] + bvr[0]) * scale);
            pk.y = f2bf((acc[nt][1] + bvr[1]) * scale);
            pk.z = f2bf((acc[nt][2] + bvr[2]) * scale);
            pk.w = f2bf((acc[nt][3] + bvr[3]) * scale);
            *(short4*)(T + (nt * 16 + lo) * 72 + wave * 16 + quad * 4) = pk;
        }
        __syncthreads();
        const int h = oyl;
        const int hb = h * 4 + b;
        short* dst = isq ? QS : KS;
#pragma unroll
        for (int s = 0; s < 4; ++s) {
            int cid = s * 256 + t;
            int ln = cid & 63, fi = cid >> 6;     // fi 0..15
            int ksd = fi & 1, rtl = fi >> 1;      // rtl 0..7
            bf16x8 v = *(const bf16x8*)(T + (rtl * 16 + (ln & 15)) * 72 + ksd * 32 + (ln >> 4) * 8);
            *(bf16x8*)(dst + (((size_t)(hb * 128 + (n0b >> 4) + rtl) * 2 + ksd) * 512 + ln * 8)) = v;
        }
    } else if (oy < 24) {
        // ---- V: T2[64][136] bf16 -> fragment-major VSu ----
        short* T2 = (short*)smem;
        float bvr[4];
#pragma unroll
        for (int r = 0; r < 4; ++r) bvr[r] = bv[o0 - 512 + wave * 16 + quad * 4 + r];
#pragma unroll
        for (int nt = 0; nt < 8; ++nt)
#pragma unroll
            for (int r = 0; r < 4; ++r) {
                int ol = wave * 16 + quad * 4 + r;
                T2[ol * 136 + nt * 16 + lo] = f2bf(acc[nt][r] + bvr[r]);
            }
        __syncthreads();
        const int h = oy - 16;
        const int hb = h * 4 + b;
#pragma unroll
        for (int s = 0; s < 4; ++s) {
            int cid = s * 256 + t;
            int ln = cid & 63, fi = cid >> 6;     // fi 0..15
            int dt = fi & 3, ksd = (fi >> 2) & 1, nbl = fi >> 3;
            int dl = dt * 16 + (ln & 15);
            int tkl = nbl * 64 + ksd * 32 + (ln >> 4) * 8;
            bf16x8 v = *(const bf16x8*)(T2 + dl * 136 + tkl);
            int nbg = (n0b >> 6) + nbl;
            *(bf16x8*)(VSu + ((size_t)(((hb * 32 + nbg) * 2 + ksd) * 4 + dt) * 64 + ln) * 8) = v;
        }
    } else {
        // ---- YP: T3[128][68] fp32 -> (b,n,d) float4 stores ----
        float* T3 = (float*)smem;
#pragma unroll
        for (int nt = 0; nt < 8; ++nt) {
            float4 f;
            f.x = acc[nt][0]; f.y = acc[nt][1]; f.z = acc[nt][2]; f.w = acc[nt][3];
            *(float4*)(T3 + (nt * 16 + lo) * 68 + wave * 16 + quad * 4) = f;
        }
        __syncthreads();
#pragma unroll
        for (int s = 0; s < 8; ++s) {
            int cid = s * 256 + t;
            int row = cid >> 4, c4 = (cid & 15) * 4;
            float4 f = *(const float4*)(T3 + row * 68 + c4);
            *(float4*)(Yo + ((size_t)(tok0 + row)) * 64 + c4) = f;
        }
    }
}

// ---------------------------------------------------------------------------
// rowsum partials over m-QUARTERS: dst[zq][hb][n] = sum over m-quarter zq of
// exp2(Q'[n].K[m]).  2048 blocks (8 blocks/CU capacity) for latency hiding.
// Quarters 0,1 -> RSp, quarters 2,3 -> RSpW (overlay of dead weight region).
// ---------------------------------------------------------------------------
__global__ __launch_bounds__(256, 6) void rowsum_mfma(
    const short* __restrict__ QS, const short* __restrict__ KS,
    float* __restrict__ RSp, float* __restrict__ RSpW)
{
    const int id = blockIdx.x;                     // 2048 blocks
    const int hb = ((id & 7) << 2) | ((id >> 3) & 3);   // h = id&7 keeps per-XCD L2 locality
    const int zq = (id >> 5) & 3;                  // m-quarter
    const int n0 = (id >> 7) * 128;
    const int t = threadIdx.x, wave = t >> 6, lane = t & 63;
    const int lo = lane & 15, quad = lane >> 4;
    const f32x4 czero = {0.f, 0.f, 0.f, 0.f};

    bf16x8 a0[2], a1[2];
#pragma unroll
    for (int s = 0; s < 2; ++s) {
        int rt = (n0 >> 4) + s * 4 + wave;
        a0[s] = *(const bf16x8*)(QS + ((size_t)(hb * 128 + rt) * 2 + 0) * 512 + lane * 8);
        a1[s] = *(const bf16x8*)(QS + ((size_t)(hb * 128 + rt) * 2 + 1) * 512 + lane * 8);
    }

    float sm[2][4];
#pragma unroll
    for (int s = 0; s < 2; ++s)
#pragma unroll
        for (int r = 0; r < 4; ++r) sm[s][r] = 0.f;

    const short* kp = KS + ((size_t)(hb * 128) * 2) * 512 + lane * 8
                    + (size_t)zq * (N_DIM / 4 / 16) * 2 * 512;
    for (int m0 = 0; m0 < N_DIM / 4; m0 += 64) {
#pragma unroll
        for (int mt = 0; mt < 4; ++mt) {
            bf16x8 b0 = *(const bf16x8*)(kp + (mt * 2 + 0) * 512);
            bf16x8 b1 = *(const bf16x8*)(kp + (mt * 2 + 1) * 512);
#pragma unroll
            for (int s = 0; s < 2; ++s) {
                f32x4 c = MFMA16(a0[s], b0, czero);
                c = MFMA16(a1[s], b1, c);
#pragma unroll
                for (int r = 0; r < 4; ++r) sm[s][r] += fx2(c[r]);
            }
        }
        kp += 8 * 512;
    }

#pragma unroll
    for (int sft = 1; sft < 16; sft <<= 1)
#pragma unroll
        for (int s = 0; s < 2; ++s)
#pragma unroll
            for (int r = 0; r < 4; ++r) sm[s][r] += __shfl_xor(sm[s][r], sft);

    if (lo == 0) {
        float* dst = (zq < 2) ? (RSp  + (size_t)zq * HB * N_DIM)
                              : (RSpW + (size_t)(zq - 2) * HB * N_DIM);
#pragma unroll
        for (int s = 0; s < 2; ++s) {
            int row = n0 + s * 64 + wave * 16 + quad * 4;
#pragma unroll
            for (int r = 0; r < 4; ++r)
                dst[(size_t)hb * N_DIM + row + r] = sm[s][r];
        }
    }
}

// ---------------------------------------------------------------------------
// VS = VSu * 1/(sum of 4 rowsum partials) — same fragment-major layout in/out
// ---------------------------------------------------------------------------
__global__ __launch_bounds__(256) void v_scale(
    const short* __restrict__ VSu, const float* __restrict__ RSp,
    const float* __restrict__ RSpW, short* __restrict__ VS)
{
    int t = blockIdx.x * 256 + threadIdx.x;     // 0..524287
    int lane = t & 63, fidx = t >> 6;
    int ks = (fidx >> 2) & 1, nb = (fidx >> 3) & 31, hb = fidx >> 8;
    int n = nb * 64 + ks * 32 + (lane >> 4) * 8;
    bf16x8 v = *(const bf16x8*)(VSu + (size_t)t * 8);
    const float* r0 = RSp  + (size_t)hb * N_DIM + n;
    const float* r1 = r0 + (size_t)HB * N_DIM;
    const float* r2 = RSpW + (size_t)hb * N_DIM + n;
    const float* r3 = r2 + (size_t)HB * N_DIM;
    bf16x8 o;
#pragma unroll
    for (int j = 0; j < 8; ++j)
        o[j] = f2bf(bf2f(v[j]) / ((r0[j] + r1[j]) + (r2[j] + r3[j])));
    *(bf16x8*)(VS + (size_t)t * 8) = o;
}

// ---------------------------------------------------------------------------
// attnout: PA_z[hb,m,d] (bf16) = sum_{n in half z} exp2(Q'.K) Vsc[n,d]
// 64-m tile x n-half -> 2048 blocks (6 blocks/CU under launch_bounds(256,6))
// to raise resident waves/SIMD from 4 to 6 (kernel is L2-latency-bound:
// MfmaUtil 28% with HBM at 7.5%).  Per-wave state shrinks vs 128-m tile:
// one K frag pair, oacc[4], c[4].  Software-pipelined K-loop as before:
//   iter i: [load Q(i+1)] [expwrite(i)] [QK-MFMA(i+1)] [PV(i)]
// QK MFMA cluster is register-only -> wrapped in s_setprio(1/0) (T5 regime:
// barrier-free, phase-diverse waves).
// ---------------------------------------------------------------------------
__global__ __launch_bounds__(256, 6) void attnout_mfma(
    const short* __restrict__ QS, const short* __restrict__ KS,
    const short* __restrict__ VS,
    short* __restrict__ PA0, short* __restrict__ PA1)
{
    const int id = blockIdx.x;                     // 2048 blocks
    const int hb = ((id & 7) << 2) | ((id >> 3) & 3);
    const int z = (id >> 5) & 1;
    const int m0 = (id >> 6) * 64;

    __shared__ __align__(16) char smem[17408];     // Pl (8 KB) / epilogue T (17.4 KB)
    short* Pl = (short*)smem;

    const int t = threadIdx.x, wave = t >> 6, lane = t & 63;
    const int lo = lane & 15, quad = lane >> 4;
    const f32x4 czero = {0.f, 0.f, 0.f, 0.f};

    bf16x8 bk0, bk1;
    {
        int rt = (m0 >> 4) + wave;
        bk0 = *(const bf16x8*)(KS + ((size_t)(hb * 128 + rt) * 2 + 0) * 512 + lane * 8);
        bk1 = *(const bf16x8*)(KS + ((size_t)(hb * 128 + rt) * 2 + 1) * 512 + lane * 8);
    }

    f32x4 oacc[4];
#pragma unroll
    for (int dt = 0; dt < 4; ++dt) oacc[dt] = czero;

    const short* qp = QS + ((size_t)(hb * 128) * 2) * 512 + lane * 8
                    + (size_t)z * (N_DIM / 2 / 16) * 2 * 512;
    const short* vp = VS + ((size_t)(hb * 32) * 8) * 512 + lane * 8
                    + (size_t)z * (N_DIM / 2 / 64) * 8 * 512;
    short* prowA = Pl + (wave * 16 + lo) * 64;
    const int lh = lo & 7;
    const int NIT = N_DIM / 2 / 64;   // 16

    f32x4 c[4];                       // E' results for the "current" iteration

    // ---- prologue: QK(0) ----
    {
#pragma unroll
        for (int nt = 0; nt < 4; ++nt) {
            bf16x8 a0 = *(const bf16x8*)(qp + (nt * 2 + 0) * 512);
            bf16x8 a1 = *(const bf16x8*)(qp + (nt * 2 + 1) * 512);
            c[nt] = MFMA16(a0, bk0, czero);
            c[nt] = MFMA16(a1, bk1, c[nt]);
        }
        qp += 8 * 512;
    }

    for (int i = 0; i < NIT - 1; ++i) {
        // ---- load Q fragments for iter i+1 (use separated by exp chain) ----
        bf16x8 a0[4], a1[4];
#pragma unroll
        for (int nt = 0; nt < 4; ++nt) {
            a0[nt] = *(const bf16x8*)(qp + (nt * 2 + 0) * 512);
            a1[nt] = *(const bf16x8*)(qp + (nt * 2 + 1) * 512);
        }
        // ---- expwrite(i): P = exp2(E') -> Pl ----
#pragma unroll
        for (int nt = 0; nt < 4; ++nt) {
            uint2 pk;
            pk.x = pk_bf16(fx2(c[nt][0]), fx2(c[nt][1]));
            pk.y = pk_bf16(fx2(c[nt][2]), fx2(c[nt][3]));
            int chunk = nt * 2 + (quad >> 1);
            *(uint2*)(prowA + (((chunk ^ lh) << 3) | ((quad & 1) << 2))) = pk;
        }
        // ---- QK-MFMA(i+1) (separates ds_write(i) from ds_read(i)) ----
        __builtin_amdgcn_s_setprio(1);
#pragma unroll
        for (int nt = 0; nt < 4; ++nt) {
            c[nt] = MFMA16(a0[nt], bk0, czero);
            c[nt] = MFMA16(a1[nt], bk1, c[nt]);
        }
        __builtin_amdgcn_s_setprio(0);
        // ---- PV(i) ----
#pragma unroll
        for (int ks = 0; ks < 2; ++ks) {
            bf16x8 ap0 = *(const bf16x8*)(prowA + (((ks * 4 + quad) ^ lh) << 3));
#pragma unroll
            for (int dt = 0; dt < 4; ++dt) {
                bf16x8 bv = *(const bf16x8*)(vp + (ks * 4 + dt) * 512);
                oacc[dt] = MFMA16(ap0, bv, oacc[dt]);
            }
        }
        qp += 8 * 512;
        vp += 8 * 512;
    }

    // ---- tail: expwrite(NIT-1) + PV(NIT-1) ----
#pragma unroll
    for (int nt = 0; nt < 4; ++nt) {
        uint2 pk;
        pk.x = pk_bf16(fx2(c[nt][0]), fx2(c[nt][1]));
        pk.y = pk_bf16(fx2(c[nt][2]), fx2(c[nt][3]));
        int chunk = nt * 2 + (quad >> 1);
        *(uint2*)(prowA + (((chunk ^ lh) << 3) | ((quad & 1) << 2))) = pk;
    }
#pragma unroll
    for (int ks = 0; ks < 2; ++ks) {
        bf16x8 ap0 = *(const bf16x8*)(prowA + (((ks * 4 + quad) ^ lh) << 3));
#pragma unroll
        for (int dt = 0; dt < 4; ++dt) {
            bf16x8 bv = *(const bf16x8*)(vp + (ks * 4 + dt) * 512);
            oacc[dt] = MFMA16(ap0, bv, oacc[dt]);
        }
    }

    // ---- epilogue: LDS transpose -> coalesced bf16 partial stores ----
    short* PA = z ? PA1 : PA0;
    float* T = (float*)smem;                      // [64][68]
    __syncthreads();                              // all Pl reads done
#pragma unroll
    for (int dt = 0; dt < 4; ++dt)
#pragma unroll
        for (int r = 0; r < 4; ++r)
            T[(wave * 16 + quad * 4 + r) * 68 + dt * 16 + lo] = oacc[dt][r];
    __syncthreads();
#pragma unroll
    for (int it = 0; it < 2; ++it) {
        int idx = it * 256 + t;                   // 0..511
        int rowl = idx >> 3, dg = (idx & 7) * 8;
        float4 f0 = *(const float4*)(T + rowl * 68 + dg);
        float4 f1 = *(const float4*)(T + rowl * 68 + dg + 4);
        uint4 o;
        o.x = pk_bf16(f0.x, f0.y);
        o.y = pk_bf16(f0.z, f0.w);
        o.z = pk_bf16(f1.x, f1.y);
        o.w = pk_bf16(f1.z, f1.w);
        int m = m0 + rowl;
        *(uint4*)(PA + ((size_t)(hb * N_DIM + m)) * 64 + dg) = o;
    }
}

// ---------------------------------------------------------------------------
// out = g/(1+g) * (PA0 + PA1) + YP/(1+g)
// ---------------------------------------------------------------------------
__global__ __launch_bounds__(256) void combine_out(
    const short* __restrict__ PA0, const short* __restrict__ PA1,
    const float* __restrict__ YP, const float* __restrict__ gamma,
    float* __restrict__ out)
{
    size_t flat = ((size_t)blockIdx.x * 256 + threadIdx.x) * 8;
    int d  = (int)(flat & 63);
    int n  = (int)((flat >> 6) & (N_DIM - 1));
    int hb = (int)(flat >> 17);
    int h = hb >> 2, b = hb & 3;
    float g = gamma[h];
    float inv = 1.f / (1.f + g);
    float gi = g * inv;
    bf16x8 p0 = *(const bf16x8*)(PA0 + flat);
    bf16x8 p1 = *(const bf16x8*)(PA1 + flat);
    const float* yp = YP + ((size_t)b * N_DIM + n) * HD + d;
    float o[8];
#pragma unroll
    for (int j = 0; j < 8; ++j)
        o[j] = gi * (bf2f(p0[j]) + bf2f(p1[j])) + inv * yp[j];
    float4 o0 = {o[0], o[1], o[2], o[3]};
    float4 o1 = {o[4], o[5], o[6], o[7]};
    *(float4*)(out + flat) = o0;
    *(float4*)(out + flat + 4) = o1;
}

// ---------------------------------------------------------------------------
extern "C" void kernel_launch(void* const* d_in, const int* in_sizes, int n_in,
                              void* d_out, int out_size, void* d_ws, size_t ws_size,
                              hipStream_t stream) {
    const float* x     = (const float*)d_in[0];
    const float* y     = (const float*)d_in[1];
    const float* Wq    = (const float*)d_in[2];
    const float* bq    = (const float*)d_in[3];
    const float* Wk    = (const float*)d_in[4];
    const float* bk    = (const float*)d_in[5];
    const float* Wv    = (const float*)d_in[6];
    const float* bv    = (const float*)d_in[7];
    const float* Wp    = (const float*)d_in[8];
    const float* gamma = (const float*)d_in[9];
    float* out = (float*)d_out;

    const size_t XEL  = (size_t)B_DIM * C_DIM * N_DIM;  // 2,097,152
    const size_t QKV  = (size_t)HB * N_DIM * HD;        // 4,194,304

    short* XS  = (short*)d_ws;
    short* YS  = XS + XEL;
    short* WSx = YS + XEL;            // 512*256
    short* WSy = WSx + 512 * C_DIM;   // 1088*256
    short* QS  = WSy + 1088 * C_DIM;
    short* KS  = QS + QKV;
    short* VSu = KS + QKV;
    short* VS  = VSu + QKV;
    float* YPb = (float*)(VS + QKV);
    float* RSp = YPb + (size_t)B_DIM * N_DIM * HD;      // 2 * HB * N (quarters 0,1)
    // overlays (dead after their producers/consumers finish):
    short* PA0 = XS;                  // XS+YS region = exactly QKV shorts
    short* PA1 = VSu;                 // VSu dead after v_scale
    float* RSpW = (float*)WSx;        // quarters 2,3: weight region dead after proj_all
                                      // (needs 512 KB; WSx+WSy = 800 KB)

    dim3 blk(256);
    cast_all<<<dim3(N_DIM / 64, C_DIM / 64, 9), blk, 0, stream>>>(
        x, y, Wq, Wk, Wv, Wp, XS, YS, WSx, WSy);

    proj_all<<<dim3(NTOK / 128, 25), blk, 0, stream>>>(
        WSx, WSy, XS, YS, bq, bk, bv, QS, KS, VSu, YPb);

    rowsum_mfma<<<dim3(2048), blk, 0, stream>>>(QS, KS, RSp, RSpW);
    v_scale<<<dim3(2048), blk, 0, stream>>>(VSu, RSp, RSpW, VS);
    attnout_mfma<<<dim3(2048), blk, 0, stream>>>(QS, KS, VS, PA0, PA1);
    combine_out<<<dim3(2048), blk, 0, stream>>>(PA0, PA1, YPb, gamma, out);
}

// Round 2
// 189.512 us; speedup vs baseline: 1.4943x; 1.4943x over previous
//
#include <hip/hip_runtime.h>
#include <math.h>

#define B_DIM 4
#define C_DIM 256
#define N_DIM 2048
#define H_DIM 8
#define HD    64
#define HB    32                 // H*B
#define NTOK  (B_DIM * N_DIM)    // 8192
#define LOG2E 1.44269504f

typedef __attribute__((ext_vector_type(8))) short bf16x8;
typedef __attribute__((ext_vector_type(4))) float f32x4;

static __device__ __forceinline__ short f2bf(float f) {          // RNE (cold paths)
    unsigned u = __builtin_bit_cast(unsigned, f);
    u += 0x7fffu + ((u >> 16) & 1u);
    return (short)(u >> 16);
}
static __device__ __forceinline__ float bf2f(short s) {
    unsigned u = ((unsigned)(unsigned short)s) << 16;
    return __builtin_bit_cast(float, u);
}
// raw v_exp_f32: exact for |x| <~ 126, skips OCML's range-guard sequence
static __device__ __forceinline__ float fx2(float x) {
#if __has_builtin(__builtin_amdgcn_exp2f)
    return __builtin_amdgcn_exp2f(x);
#else
    return exp2f(x);
#endif
}
// pack two fp32 -> two bf16 in one dword (HW packed cvt when available)
static __device__ __forceinline__ unsigned pk_bf16(float a, float b) {
#if __has_builtin(__builtin_amdgcn_cvt_pk_bf16_f32)
    auto v = __builtin_amdgcn_cvt_pk_bf16_f32(a, b);
    return __builtin_bit_cast(unsigned, v);
#else
    unsigned ua = __builtin_bit_cast(unsigned, a);
    unsigned ub = __builtin_bit_cast(unsigned, b);
    return ((ua + 0x8000u) >> 16) | ((ub + 0x8000u) & 0xffff0000u);
#endif
}

#define MFMA16(A, Bv, Cv) __builtin_amdgcn_mfma_f32_16x16x32_bf16(A, Bv, Cv, 0, 0, 0)

// Fragment-major layouts (fragment = 64 lanes x 16 B = 1 KB contiguous):
//   QS/KS(hb, rt, ks, lane, j) = M[hb][n = rt*16 + (lane&15)][d = ks*32 + (lane>>4)*8 + j]
//   (QS holds Q * log2e so exp() becomes exp2())
//   VS(hb, nb, ks, dt, lane, j) = V[hb][d = dt*16+(lane&15)][n = nb*64+ks*32+(lane>>4)*8+j]
//   XS/YS(rt, ks, lane, j) = X[tok = rt*16+(lane&15)][c = ks*32+(lane>>4)*8+j]
//   WS(ot, ks, lane, j)    = W[o  = ot*16+(lane&15)][c = ks*32+(lane>>4)*8+j]

// ---------------------------------------------------------------------------
// cast+transpose to fragment-major (z 0..7: x/y batches) + weights (z == 8)
// ---------------------------------------------------------------------------
__global__ __launch_bounds__(256) void cast_all(
    const float* __restrict__ X, const float* __restrict__ Y,
    const float* __restrict__ Wq, const float* __restrict__ Wk,
    const float* __restrict__ Wv, const float* __restrict__ Wp,
    short* __restrict__ XS, short* __restrict__ YS,
    short* __restrict__ WSx, short* __restrict__ WSy)
{
    const int z = blockIdx.z;
    const int t = threadIdx.x;

    if (z == 8) {   // ---- weights: Wq -> WSx (256 chunks); Wk|Wv|Wp -> WSy (544) ----
        int base = (blockIdx.y * 32 + blockIdx.x) * 256 + t;   // 0..32767
#pragma unroll
        for (int rep = 0; rep < 2; ++rep) {
            int gid = base + rep * 32768;                       // 0..65535
            if (gid >= 51200) break;
            int lane = gid & 63, chunk = gid >> 6;              // chunk 0..799
            int lo = lane & 15, quad = lane >> 4;
            const float* src; short* dst;
            if (chunk < 256) {
                int ot = chunk >> 3, ks = chunk & 7;
                src = Wq + (size_t)(ot * 16 + lo) * C_DIM + ks * 32 + quad * 8;
                dst = WSx + (size_t)chunk * 512 + lane * 8;
            } else {
                int ch = chunk - 256;
                int ot = ch >> 3, ks = ch & 7;
                int row = ot * 16 + lo;
                const float* basep = (row < 512) ? (Wk + (size_t)row * C_DIM)
                                   : (row < 1024) ? (Wv + (size_t)(row - 512) * C_DIM)
                                                  : (Wp + (size_t)(row - 1024) * C_DIM);
                src = basep + ks * 32 + quad * 8;
                dst = WSy + (size_t)ch * 512 + lane * 8;
            }
            bf16x8 o;
#pragma unroll
            for (int j = 0; j < 8; ++j) o[j] = f2bf(src[j]);
            *(bf16x8*)dst = o;
        }
        return;
    }

    const float* src = (z < 4) ? X : Y;
    short* dst = (z < 4) ? XS : YS;
    const int b = z & 3, c0 = blockIdx.y * 64, n0 = blockIdx.x * 64;
    __shared__ float L[64][65];   // [c_local][n_local]
    for (int i = t; i < 4096; i += 256) {
        int cc = i >> 6, nn = i & 63;
        L[cc][nn] = src[((size_t)b * C_DIM + c0 + cc) * N_DIM + n0 + nn];
    }
    __syncthreads();
#pragma unroll
    for (int half = 0; half < 2; ++half) {
        int cid = half * 256 + t;
        int lane = cid & 63, fi = cid >> 6;      // fi 0..7
        int ksl = fi & 1, rtl = fi >> 1;         // rtl 0..3
        int lo = lane & 15, quad = lane >> 4;
        bf16x8 o;
#pragma unroll
        for (int j = 0; j < 8; ++j) o[j] = f2bf(L[ksl * 32 + quad * 8 + j][rtl * 16 + lo]);
        int rt = b * 128 + (n0 >> 4) + rtl;
        int ks = (c0 >> 5) + ksl;
        *(bf16x8*)(dst + ((size_t)(rt * 8 + ks) * 64 + lane) * 8) = o;
    }
}

// ---------------------------------------------------------------------------
// Merged MFMA projection, all loads coalesced fragment loads.
// oy<8: Q=(Wq x + bq)*log2e -> QS. oy 8..15: K -> KS. oy 16..23: V -> VSu.
// oy==24: YP fp32 (b,n,d). Epilogue: LDS transpose -> coalesced 16B stores.
// ---------------------------------------------------------------------------
__global__ __launch_bounds__(256) void proj_all(
    const short* __restrict__ WSx, const short* __restrict__ WSy,
    const short* __restrict__ XS, const short* __restrict__ YS,
    const float* __restrict__ bq, const float* __restrict__ bk,
    const float* __restrict__ bv,
    short* __restrict__ QS, short* __restrict__ KS,
    short* __restrict__ VSu, float* __restrict__ Yo)
{
    const int oy = blockIdx.y;
    const bool isq = oy < 8;
    const short* WS = isq ? WSx : WSy;
    const short* Xs = isq ? XS : YS;
    const int oyl = isq ? oy : oy - 8;
    const int o0 = oyl * 64;
    const int tok0 = blockIdx.x * 128;
    const int t = threadIdx.x, wave = t >> 6, lane = t & 63;
    const int lo = lane & 15, quad = lane >> 4;

    __shared__ __align__(16) char smem[34816];

    const int ot = oyl * 4 + wave;
    const int rt0 = tok0 >> 4;
    const f32x4 czero = {0.f, 0.f, 0.f, 0.f};

    f32x4 acc[8];
#pragma unroll
    for (int i = 0; i < 8; ++i) acc[i] = czero;

#pragma unroll 2
    for (int ks = 0; ks < 8; ++ks) {
        bf16x8 a = *(const bf16x8*)(WS + ((size_t)(ot * 8 + ks) * 64 + lane) * 8);
#pragma unroll
        for (int nt = 0; nt < 8; ++nt) {
            bf16x8 bx = *(const bf16x8*)(Xs + ((size_t)((rt0 + nt) * 8 + ks) * 64 + lane) * 8);
            acc[nt] = MFMA16(a, bx, acc[nt]);
        }
    }

    const int b = tok0 >> 11;
    const int n0b = tok0 & (N_DIM - 1);

    if (oy < 16) {
        // ---- Q or K: T[128][72] bf16 -> fragment-major QS/KS ----
        short* T = (short*)smem;
        const float* bias = isq ? bq : bk;
        const float scale = isq ? LOG2E : 1.f;
        float bvr[4];
#pragma unroll
        for (int r = 0; r < 4; ++r) bvr[r] = bias[o0 + wave * 16 + quad * 4 + r];
#pragma unroll
        for (int nt = 0; nt < 8; ++nt) {
            short4 pk;
            pk.x = f2bf((acc[nt][0] + bvr[0]) * scale);
            pk.y = f2bf((acc[nt][1] + bvr[1]) * scale);
            pk.z = f2bf((acc[nt][2] + bvr[2]) * scale);
            pk.w = f2bf((acc[nt][3] + bvr[3]) * scale);
            *(short4*)(T + (nt * 16 + lo) * 72 + wave * 16 + quad * 4) = pk;
        }
        __syncthreads();
        const int h = oyl;
        const int hb = h * 4 + b;
        short* dst = isq ? QS : KS;
#pragma unroll
        for (int s = 0; s < 4; ++s) {
            int cid = s * 256 + t;
            int ln = cid & 63, fi = cid >> 6;     // fi 0..15
            int ksd = fi & 1, rtl = fi >> 1;      // rtl 0..7
            bf16x8 v = *(const bf16x8*)(T + (rtl * 16 + (ln & 15)) * 72 + ksd * 32 + (ln >> 4) * 8);
            *(bf16x8*)(dst + (((size_t)(hb * 128 + (n0b >> 4) + rtl) * 2 + ksd) * 512 + ln * 8)) = v;
        }
    } else if (oy < 24) {
        // ---- V: T2[64][136] bf16 -> fragment-major VSu ----
        short* T2 = (short*)smem;
        float bvr[4];
#pragma unroll
        for (int r = 0; r < 4; ++r) bvr[r] = bv[o0 - 512 + wave * 16 + quad * 4 + r];
#pragma unroll
        for (int nt = 0; nt < 8; ++nt)
#pragma unroll
            for (int r = 0; r < 4; ++r) {
                int ol = wave * 16 + quad * 4 + r;
                T2[ol * 136 + nt * 16 + lo] = f2bf(acc[nt][r] + bvr[r]);
            }
        __syncthreads();
        const int h = oy - 16;
        const int hb = h * 4 + b;
#pragma unroll
        for (int s = 0; s < 4; ++s) {
            int cid = s * 256 + t;
            int ln = cid & 63, fi = cid >> 6;     // fi 0..15
            int dt = fi & 3, ksd = (fi >> 2) & 1, nbl = fi >> 3;
            int dl = dt * 16 + (ln & 15);
            int tkl = nbl * 64 + ksd * 32 + (ln >> 4) * 8;
            bf16x8 v = *(const bf16x8*)(T2 + dl * 136 + tkl);
            int nbg = (n0b >> 6) + nbl;
            *(bf16x8*)(VSu + ((size_t)(((hb * 32 + nbg) * 2 + ksd) * 4 + dt) * 64 + ln) * 8) = v;
        }
    } else {
        // ---- YP: T3[128][68] fp32 -> (b,n,d) float4 stores ----
        float* T3 = (float*)smem;
#pragma unroll
        for (int nt = 0; nt < 8; ++nt) {
            float4 f;
            f.x = acc[nt][0]; f.y = acc[nt][1]; f.z = acc[nt][2]; f.w = acc[nt][3];
            *(float4*)(T3 + (nt * 16 + lo) * 68 + wave * 16 + quad * 4) = f;
        }
        __syncthreads();
#pragma unroll
        for (int s = 0; s < 8; ++s) {
            int cid = s * 256 + t;
            int row = cid >> 4, c4 = (cid & 15) * 4;
            float4 f = *(const float4*)(T3 + row * 68 + c4);
            *(float4*)(Yo + ((size_t)(tok0 + row)) * 64 + c4) = f;
        }
    }
}

// ---------------------------------------------------------------------------
// rowsum partials over m-QUARTERS, 256-n tile per block (4 Q frag-pairs/wave
// -> 32 MFMAs per 8 KB of K streamed = 2x arithmetic intensity of the old
// 128-n version; the K stream is wave-redundant so intensity is the lever).
// 1024 blocks. Quarters 0,1 -> RSp; 2,3 -> RSpW (dead-weight-region overlay).
// ---------------------------------------------------------------------------
__global__ __launch_bounds__(256, 4) void rowsum_mfma(
    const short* __restrict__ QS, const short* __restrict__ KS,
    float* __restrict__ RSp, float* __restrict__ RSpW)
{
    const int id = blockIdx.x;                     // 1024 blocks
    const int hb = ((id & 7) << 2) | ((id >> 3) & 3);   // h = id&7 -> XCD L2 locality
    const int zq = (id >> 5) & 3;                  // m-quarter
    const int n0 = (id >> 7) * 256;                // 8 n-tiles
    const int t = threadIdx.x, wave = t >> 6, lane = t & 63;
    const int lo = lane & 15, quad = lane >> 4;
    const f32x4 czero = {0.f, 0.f, 0.f, 0.f};

    bf16x8 a0[4], a1[4];
#pragma unroll
    for (int s = 0; s < 4; ++s) {
        int rt = (n0 >> 4) + s * 4 + wave;
        a0[s] = *(const bf16x8*)(QS + ((size_t)(hb * 128 + rt) * 2 + 0) * 512 + lane * 8);
        a1[s] = *(const bf16x8*)(QS + ((size_t)(hb * 128 + rt) * 2 + 1) * 512 + lane * 8);
    }

    float sm[4][4];
#pragma unroll
    for (int s = 0; s < 4; ++s)
#pragma unroll
        for (int r = 0; r < 4; ++r) sm[s][r] = 0.f;

    const short* kp = KS + ((size_t)(hb * 128) * 2) * 512 + lane * 8
                    + (size_t)zq * (N_DIM / 4 / 16) * 2 * 512;
    for (int m0 = 0; m0 < N_DIM / 4; m0 += 64) {
#pragma unroll
        for (int mt = 0; mt < 4; ++mt) {
            bf16x8 b0 = *(const bf16x8*)(kp + (mt * 2 + 0) * 512);
            bf16x8 b1 = *(const bf16x8*)(kp + (mt * 2 + 1) * 512);
#pragma unroll
            for (int s = 0; s < 4; ++s) {
                f32x4 c = MFMA16(a0[s], b0, czero);
                c = MFMA16(a1[s], b1, c);
#pragma unroll
                for (int r = 0; r < 4; ++r) sm[s][r] += fx2(c[r]);
            }
        }
        kp += 8 * 512;
    }

#pragma unroll
    for (int sft = 1; sft < 16; sft <<= 1)
#pragma unroll
        for (int s = 0; s < 4; ++s)
#pragma unroll
            for (int r = 0; r < 4; ++r) sm[s][r] += __shfl_xor(sm[s][r], sft);

    if (lo == 0) {
        float* dst = (zq < 2) ? (RSp  + (size_t)zq * HB * N_DIM)
                              : (RSpW + (size_t)(zq - 2) * HB * N_DIM);
#pragma unroll
        for (int s = 0; s < 4; ++s) {
            int row = n0 + s * 64 + wave * 16 + quad * 4;
#pragma unroll
            for (int r = 0; r < 4; ++r)
                dst[(size_t)hb * N_DIM + row + r] = sm[s][r];
        }
    }
}

// ---------------------------------------------------------------------------
// VS = VSu * 1/(sum of 4 rowsum partials) — same fragment-major layout in/out
// ---------------------------------------------------------------------------
__global__ __launch_bounds__(256) void v_scale(
    const short* __restrict__ VSu, const float* __restrict__ RSp,
    const float* __restrict__ RSpW, short* __restrict__ VS)
{
    int t = blockIdx.x * 256 + threadIdx.x;     // 0..524287
    int lane = t & 63, fidx = t >> 6;
    int ks = (fidx >> 2) & 1, nb = (fidx >> 3) & 31, hb = fidx >> 8;
    int n = nb * 64 + ks * 32 + (lane >> 4) * 8;
    bf16x8 v = *(const bf16x8*)(VSu + (size_t)t * 8);
    const float* r0 = RSp  + (size_t)hb * N_DIM + n;
    const float* r1 = r0 + (size_t)HB * N_DIM;
    const float* r2 = RSpW + (size_t)hb * N_DIM + n;
    const float* r3 = r2 + (size_t)HB * N_DIM;
    bf16x8 o;
#pragma unroll
    for (int j = 0; j < 8; ++j)
        o[j] = f2bf(bf2f(v[j]) / ((r0[j] + r1[j]) + (r2[j] + r3[j])));
    *(bf16x8*)(VS + (size_t)t * 8) = o;
}

// ---------------------------------------------------------------------------
// attnout: PA_z[hb,m,d] (bf16) = sum_{n in half z} exp2(Q'.K) Vsc[n,d]
// 256-m tile x n-half -> 512 blocks (2/CU). Each wave holds K for 64 m-rows
// (4 frag pairs) so every streamed Q/V byte feeds 2x the MFMAs of the old
// 128-m version: 64 MFMAs per 16 KB = 64 FLOP/B from L2, moving the kernel
// from L2-BW-bound (~21 TB/s measured) toward the MFMA roofline. Q/V streams
// are wave-redundant; total L2 traffic halves vs round 0 (512 MB).
// Software-pipelined K-loop: iter i = [load Q(i+1)][expwrite(i)][QK(i+1)][PV(i)]
// ---------------------------------------------------------------------------
__global__ __launch_bounds__(256, 2) void attnout_mfma(
    const short* __restrict__ QS, const short* __restrict__ KS,
    const short* __restrict__ VS,
    short* __restrict__ PA0, short* __restrict__ PA1)
{
    const int id = blockIdx.x;                     // 512 blocks
    const int hb = ((id & 7) << 2) | ((id >> 3) & 3);
    const int z = (id >> 5) & 1;
    const int m0 = (id >> 6) * 256;                // 8 m-tiles

    __shared__ __align__(16) char smem[32768];     // Pl 4x8KB / epilogue T 17.4 KB
    short* Pl = (short*)smem;

    const int t = threadIdx.x, wave = t >> 6, lane = t & 63;
    const int lo = lane & 15, quad = lane >> 4;
    const f32x4 czero = {0.f, 0.f, 0.f, 0.f};

    // K fragments for the wave's 4 m-16-chunks (m-stripe s: rows s*64+wave*16+lo)
    bf16x8 bk0[4], bk1[4];
#pragma unroll
    for (int s = 0; s < 4; ++s) {
        int rt = (m0 >> 4) + s * 4 + wave;
        bk0[s] = *(const bf16x8*)(KS + ((size_t)(hb * 128 + rt) * 2 + 0) * 512 + lane * 8);
        bk1[s] = *(const bf16x8*)(KS + ((size_t)(hb * 128 + rt) * 2 + 1) * 512 + lane * 8);
    }

    f32x4 oacc[4][4];                 // [s][dt]
#pragma unroll
    for (int s = 0; s < 4; ++s)
#pragma unroll
        for (int dt = 0; dt < 4; ++dt) oacc[s][dt] = czero;

    const short* qp = QS + ((size_t)(hb * 128) * 2) * 512 + lane * 8
                    + (size_t)z * (N_DIM / 2 / 16) * 2 * 512;
    const short* vp = VS + ((size_t)(hb * 32) * 8) * 512 + lane * 8
                    + (size_t)z * (N_DIM / 2 / 64) * 8 * 512;
    short* prow = Pl + (wave * 16 + lo) * 64;      // + s*4096 selects P stripe
    const int lh = lo & 7;
    const int NIT = N_DIM / 2 / 64;   // 16

    f32x4 c[4][4];                    // E' [nt][s] for the "current" iteration

    // ---- prologue: QK(0) ----
    {
#pragma unroll
        for (int nt = 0; nt < 4; ++nt) {
            bf16x8 a0 = *(const bf16x8*)(qp + (nt * 2 + 0) * 512);
            bf16x8 a1 = *(const bf16x8*)(qp + (nt * 2 + 1) * 512);
#pragma unroll
            for (int s = 0; s < 4; ++s) {
                c[nt][s] = MFMA16(a0, bk0[s], czero);
                c[nt][s] = MFMA16(a1, bk1[s], c[nt][s]);
            }
        }
        qp += 8 * 512;
    }

    for (int i = 0; i < NIT - 1; ++i) {
        // ---- load Q fragments for iter i+1 (use separated by exp chain) ----
        bf16x8 a0[4], a1[4];
#pragma unroll
        for (int nt = 0; nt < 4; ++nt) {
            a0[nt] = *(const bf16x8*)(qp + (nt * 2 + 0) * 512);
            a1[nt] = *(const bf16x8*)(qp + (nt * 2 + 1) * 512);
        }
        // ---- expwrite(i): P = exp2(E') -> Pl stripes ----
#pragma unroll
        for (int nt = 0; nt < 4; ++nt)
#pragma unroll
            for (int s = 0; s < 4; ++s) {
                uint2 pk;
                pk.x = pk_bf16(fx2(c[nt][s][0]), fx2(c[nt][s][1]));
                pk.y = pk_bf16(fx2(c[nt][s][2]), fx2(c[nt][s][3]));
                int chunk = nt * 2 + (quad >> 1);
                *(uint2*)(prow + s * 4096 + (((chunk ^ lh) << 3) | ((quad & 1) << 2))) = pk;
            }
        // ---- QK-MFMA(i+1) (separates ds_write(i) from ds_read(i)) ----
        __builtin_amdgcn_s_setprio(1);
#pragma unroll
        for (int nt = 0; nt < 4; ++nt)
#pragma unroll
            for (int s = 0; s < 4; ++s) {
                c[nt][s] = MFMA16(a0[nt], bk0[s], czero);
                c[nt][s] = MFMA16(a1[nt], bk1[s], c[nt][s]);
            }
        __builtin_amdgcn_s_setprio(0);
        // ---- PV(i) ----
#pragma unroll
        for (int ks = 0; ks < 2; ++ks) {
            bf16x8 ap[4];
#pragma unroll
            for (int s = 0; s < 4; ++s)
                ap[s] = *(const bf16x8*)(prow + s * 4096 + (((ks * 4 + quad) ^ lh) << 3));
#pragma unroll
            for (int dt = 0; dt < 4; ++dt) {
                bf16x8 bv = *(const bf16x8*)(vp + (ks * 4 + dt) * 512);
#pragma unroll
                for (int s = 0; s < 4; ++s)
                    oacc[s][dt] = MFMA16(ap[s], bv, oacc[s][dt]);
            }
        }
        qp += 8 * 512;
        vp += 8 * 512;
    }

    // ---- tail: expwrite(NIT-1) + PV(NIT-1) ----
#pragma unroll
    for (int nt = 0; nt < 4; ++nt)
#pragma unroll
        for (int s = 0; s < 4; ++s) {
            uint2 pk;
            pk.x = pk_bf16(fx2(c[nt][s][0]), fx2(c[nt][s][1]));
            pk.y = pk_bf16(fx2(c[nt][s][2]), fx2(c[nt][s][3]));
            int chunk = nt * 2 + (quad >> 1);
            *(uint2*)(prow + s * 4096 + (((chunk ^ lh) << 3) | ((quad & 1) << 2))) = pk;
        }
#pragma unroll
    for (int ks = 0; ks < 2; ++ks) {
        bf16x8 ap[4];
#pragma unroll
        for (int s = 0; s < 4; ++s)
            ap[s] = *(const bf16x8*)(prow + s * 4096 + (((ks * 4 + quad) ^ lh) << 3));
#pragma unroll
        for (int dt = 0; dt < 4; ++dt) {
            bf16x8 bv = *(const bf16x8*)(vp + (ks * 4 + dt) * 512);
#pragma unroll
            for (int s = 0; s < 4; ++s)
                oacc[s][dt] = MFMA16(ap[s], bv, oacc[s][dt]);
        }
    }

    // ---- epilogue: LDS transpose -> coalesced bf16 partial stores ----
    short* PA = z ? PA1 : PA0;
    float* T = (float*)smem;                      // [64][68]
#pragma unroll
    for (int s = 0; s < 4; ++s) {
        __syncthreads();                          // Pl / previous T reads done
#pragma unroll
        for (int dt = 0; dt < 4; ++dt)
#pragma unroll
            for (int r = 0; r < 4; ++r)
                T[(wave * 16 + quad * 4 + r) * 68 + dt * 16 + lo] = oacc[s][dt][r];
        __syncthreads();
#pragma unroll
        for (int it = 0; it < 2; ++it) {
            int idx = it * 256 + t;               // 0..511
            int rowl = idx >> 3, dg = (idx & 7) * 8;
            float4 f0 = *(const float4*)(T + rowl * 68 + dg);
            float4 f1 = *(const float4*)(T + rowl * 68 + dg + 4);
            uint4 o;
            o.x = pk_bf16(f0.x, f0.y);
            o.y = pk_bf16(f0.z, f0.w);
            o.z = pk_bf16(f1.x, f1.y);
            o.w = pk_bf16(f1.z, f1.w);
            int m = m0 + s * 64 + rowl;
            *(uint4*)(PA + ((size_t)(hb * N_DIM + m)) * 64 + dg) = o;
        }
    }
}

// ---------------------------------------------------------------------------
// out = g/(1+g) * (PA0 + PA1) + YP/(1+g)
// ---------------------------------------------------------------------------
__global__ __launch_bounds__(256) void combine_out(
    const short* __restrict__ PA0, const short* __restrict__ PA1,
    const float* __restrict__ YP, const float* __restrict__ gamma,
    float* __restrict__ out)
{
    size_t flat = ((size_t)blockIdx.x * 256 + threadIdx.x) * 8;
    int d  = (int)(flat & 63);
    int n  = (int)((flat >> 6) & (N_DIM - 1));
    int hb = (int)(flat >> 17);
    int h = hb >> 2, b = hb & 3;
    float g = gamma[h];
    float inv = 1.f / (1.f + g);
    float gi = g * inv;
    bf16x8 p0 = *(const bf16x8*)(PA0 + flat);
    bf16x8 p1 = *(const bf16x8*)(PA1 + flat);
    const float* yp = YP + ((size_t)b * N_DIM + n) * HD + d;
    float o[8];
#pragma unroll
    for (int j = 0; j < 8; ++j)
        o[j] = gi * (bf2f(p0[j]) + bf2f(p1[j])) + inv * yp[j];
    float4 o0 = {o[0], o[1], o[2], o[3]};
    float4 o1 = {o[4], o[5], o[6], o[7]};
    *(float4*)(out + flat) = o0;
    *(float4*)(out + flat + 4) = o1;
}

// ---------------------------------------------------------------------------
extern "C" void kernel_launch(void* const* d_in, const int* in_sizes, int n_in,
                              void* d_out, int out_size, void* d_ws, size_t ws_size,
                              hipStream_t stream) {
    const float* x     = (const float*)d_in[0];
    const float* y     = (const float*)d_in[1];
    const float* Wq    = (const float*)d_in[2];
    const float* bq    = (const float*)d_in[3];
    const float* Wk    = (const float*)d_in[4];
    const float* bk    = (const float*)d_in[5];
    const float* Wv    = (const float*)d_in[6];
    const float* bv    = (const float*)d_in[7];
    const float* Wp    = (const float*)d_in[8];
    const float* gamma = (const float*)d_in[9];
    float* out = (float*)d_out;

    const size_t XEL  = (size_t)B_DIM * C_DIM * N_DIM;  // 2,097,152
    const size_t QKV  = (size_t)HB * N_DIM * HD;        // 4,194,304

    short* XS  = (short*)d_ws;
    short* YS  = XS + XEL;
    short* WSx = YS + XEL;            // 512*256
    short* WSy = WSx + 512 * C_DIM;   // 1088*256
    short* QS  = WSy + 1088 * C_DIM;
    short* KS  = QS + QKV;
    short* VSu = KS + QKV;
    short* VS  = VSu + QKV;
    float* YPb = (float*)(VS + QKV);
    float* RSp = YPb + (size_t)B_DIM * N_DIM * HD;      // 2 * HB * N (quarters 0,1)
    // overlays (dead after their producers/consumers finish):
    short* PA0 = XS;                  // XS+YS region = exactly QKV shorts
    short* PA1 = VSu;                 // VSu dead after v_scale
    float* RSpW = (float*)WSx;        // quarters 2,3: weight region dead after proj_all
                                      // (needs 512 KB; WSx+WSy = 800 KB)

    dim3 blk(256);
    cast_all<<<dim3(N_DIM / 64, C_DIM / 64, 9), blk, 0, stream>>>(
        x, y, Wq, Wk, Wv, Wp, XS, YS, WSx, WSy);

    proj_all<<<dim3(NTOK / 128, 25), blk, 0, stream>>>(
        WSx, WSy, XS, YS, bq, bk, bv, QS, KS, VSu, YPb);

    rowsum_mfma<<<dim3(1024), blk, 0, stream>>>(QS, KS, RSp, RSpW);
    v_scale<<<dim3(2048), blk, 0, stream>>>(VSu, RSp, RSpW, VS);
    attnout_mfma<<<dim3(512), blk, 0, stream>>>(QS, KS, VS, PA0, PA1);
    combine_out<<<dim3(2048), blk, 0, stream>>>(PA0, PA1, YPb, gamma, out);
}

// Round 3
// 184.755 us; speedup vs baseline: 1.5328x; 1.0258x over previous
//
#include <hip/hip_runtime.h>
#include <math.h>
#include <stdint.h>

#define B_DIM 4
#define C_DIM 256
#define N_DIM 2048
#define H_DIM 8
#define HD    64
#define HB    32                 // H*B
#define NTOK  (B_DIM * N_DIM)    // 8192
#define LOG2E 1.44269504f

typedef __attribute__((ext_vector_type(8))) short bf16x8;
typedef __attribute__((ext_vector_type(4))) float f32x4;

static __device__ __forceinline__ short f2bf(float f) {          // RNE (cold paths)
    unsigned u = __builtin_bit_cast(unsigned, f);
    u += 0x7fffu + ((u >> 16) & 1u);
    return (short)(u >> 16);
}
static __device__ __forceinline__ float bf2f(short s) {
    unsigned u = ((unsigned)(unsigned short)s) << 16;
    return __builtin_bit_cast(float, u);
}
// raw v_exp_f32: exact for |x| <~ 126, skips OCML's range-guard sequence
static __device__ __forceinline__ float fx2(float x) {
#if __has_builtin(__builtin_amdgcn_exp2f)
    return __builtin_amdgcn_exp2f(x);
#else
    return exp2f(x);
#endif
}
// pack two fp32 -> two bf16 in one dword (HW packed cvt when available)
static __device__ __forceinline__ unsigned pk_bf16(float a, float b) {
#if __has_builtin(__builtin_amdgcn_cvt_pk_bf16_f32)
    auto v = __builtin_amdgcn_cvt_pk_bf16_f32(a, b);
    return __builtin_bit_cast(unsigned, v);
#else
    unsigned ua = __builtin_bit_cast(unsigned, a);
    unsigned ub = __builtin_bit_cast(unsigned, b);
    return ((ua + 0x8000u) >> 16) | ((ub + 0x8000u) & 0xffff0000u);
#endif
}

// async global->LDS 16B/lane: dest = wave-uniform LDS base + lane*16,
// src = per-lane global address. Fallback: plain reg round-trip.
static __device__ __forceinline__ void gll16(const void* g, void* ldsbase, int lane) {
#if __has_builtin(__builtin_amdgcn_global_load_lds)
    __builtin_amdgcn_global_load_lds(
        (const __attribute__((address_space(1))) void*)(uintptr_t)(g),
        (__attribute__((address_space(3))) void*)(uintptr_t)(ldsbase), 16, 0, 0);
#else
    *(bf16x8*)((char*)ldsbase + lane * 16) = *(const bf16x8*)g;
#endif
}

#define MFMA16(A, Bv, Cv) __builtin_amdgcn_mfma_f32_16x16x32_bf16(A, Bv, Cv, 0, 0, 0)

// Fragment-major layouts (fragment = 64 lanes x 16 B = 1 KB contiguous):
//   QS/KS(hb, rt, ks, lane, j) = M[hb][n = rt*16 + (lane&15)][d = ks*32 + (lane>>4)*8 + j]
//   (QS holds Q * log2e so exp() becomes exp2())
//   VS(hb, nb, ks, dt, lane, j) = V[hb][d = dt*16+(lane&15)][n = nb*64+ks*32+(lane>>4)*8+j]
//   XS/YS(rt, ks, lane, j) = X[tok = rt*16+(lane&15)][c = ks*32+(lane>>4)*8+j]
//   WS(ot, ks, lane, j)    = W[o  = ot*16+(lane&15)][c = ks*32+(lane>>4)*8+j]

// ---------------------------------------------------------------------------
// cast+transpose to fragment-major (z 0..7: x/y batches) + weights (z == 8)
// ---------------------------------------------------------------------------
__global__ __launch_bounds__(256) void cast_all(
    const float* __restrict__ X, const float* __restrict__ Y,
    const float* __restrict__ Wq, const float* __restrict__ Wk,
    const float* __restrict__ Wv, const float* __restrict__ Wp,
    short* __restrict__ XS, short* __restrict__ YS,
    short* __restrict__ WSx, short* __restrict__ WSy)
{
    const int z = blockIdx.z;
    const int t = threadIdx.x;

    if (z == 8) {   // ---- weights: Wq -> WSx (256 chunks); Wk|Wv|Wp -> WSy (544) ----
        int base = (blockIdx.y * 32 + blockIdx.x) * 256 + t;   // 0..32767
#pragma unroll
        for (int rep = 0; rep < 2; ++rep) {
            int gid = base + rep * 32768;                       // 0..65535
            if (gid >= 51200) break;
            int lane = gid & 63, chunk = gid >> 6;              // chunk 0..799
            int lo = lane & 15, quad = lane >> 4;
            const float* src; short* dst;
            if (chunk < 256) {
                int ot = chunk >> 3, ks = chunk & 7;
                src = Wq + (size_t)(ot * 16 + lo) * C_DIM + ks * 32 + quad * 8;
                dst = WSx + (size_t)chunk * 512 + lane * 8;
            } else {
                int ch = chunk - 256;
                int ot = ch >> 3, ks = ch & 7;
                int row = ot * 16 + lo;
                const float* basep = (row < 512) ? (Wk + (size_t)row * C_DIM)
                                   : (row < 1024) ? (Wv + (size_t)(row - 512) * C_DIM)
                                                  : (Wp + (size_t)(row - 1024) * C_DIM);
                src = basep + ks * 32 + quad * 8;
                dst = WSy + (size_t)ch * 512 + lane * 8;
            }
            bf16x8 o;
#pragma unroll
            for (int j = 0; j < 8; ++j) o[j] = f2bf(src[j]);
            *(bf16x8*)dst = o;
        }
        return;
    }

    const float* src = (z < 4) ? X : Y;
    short* dst = (z < 4) ? XS : YS;
    const int b = z & 3, c0 = blockIdx.y * 64, n0 = blockIdx.x * 64;
    __shared__ float L[64][65];   // [c_local][n_local]
    for (int i = t; i < 4096; i += 256) {
        int cc = i >> 6, nn = i & 63;
        L[cc][nn] = src[((size_t)b * C_DIM + c0 + cc) * N_DIM + n0 + nn];
    }
    __syncthreads();
#pragma unroll
    for (int half = 0; half < 2; ++half) {
        int cid = half * 256 + t;
        int lane = cid & 63, fi = cid >> 6;      // fi 0..7
        int ksl = fi & 1, rtl = fi >> 1;         // rtl 0..3
        int lo = lane & 15, quad = lane >> 4;
        bf16x8 o;
#pragma unroll
        for (int j = 0; j < 8; ++j) o[j] = f2bf(L[ksl * 32 + quad * 8 + j][rtl * 16 + lo]);
        int rt = b * 128 + (n0 >> 4) + rtl;
        int ks = (c0 >> 5) + ksl;
        *(bf16x8*)(dst + ((size_t)(rt * 8 + ks) * 64 + lane) * 8) = o;
    }
}

// ---------------------------------------------------------------------------
// Merged MFMA projection, all loads coalesced fragment loads.
// oy<8: Q=(Wq x + bq)*log2e -> QS. oy 8..15: K -> KS. oy 16..23: V -> VSu.
// oy==24: YP fp32 (b,n,d). Epilogue: LDS transpose -> coalesced 16B stores.
// ---------------------------------------------------------------------------
__global__ __launch_bounds__(256) void proj_all(
    const short* __restrict__ WSx, const short* __restrict__ WSy,
    const short* __restrict__ XS, const short* __restrict__ YS,
    const float* __restrict__ bq, const float* __restrict__ bk,
    const float* __restrict__ bv,
    short* __restrict__ QS, short* __restrict__ KS,
    short* __restrict__ VSu, float* __restrict__ Yo)
{
    const int oy = blockIdx.y;
    const bool isq = oy < 8;
    const short* WS = isq ? WSx : WSy;
    const short* Xs = isq ? XS : YS;
    const int oyl = isq ? oy : oy - 8;
    const int o0 = oyl * 64;
    const int tok0 = blockIdx.x * 128;
    const int t = threadIdx.x, wave = t >> 6, lane = t & 63;
    const int lo = lane & 15, quad = lane >> 4;

    __shared__ __align__(16) char smem[34816];

    const int ot = oyl * 4 + wave;
    const int rt0 = tok0 >> 4;
    const f32x4 czero = {0.f, 0.f, 0.f, 0.f};

    f32x4 acc[8];
#pragma unroll
    for (int i = 0; i < 8; ++i) acc[i] = czero;

#pragma unroll 2
    for (int ks = 0; ks < 8; ++ks) {
        bf16x8 a = *(const bf16x8*)(WS + ((size_t)(ot * 8 + ks) * 64 + lane) * 8);
#pragma unroll
        for (int nt = 0; nt < 8; ++nt) {
            bf16x8 bx = *(const bf16x8*)(Xs + ((size_t)((rt0 + nt) * 8 + ks) * 64 + lane) * 8);
            acc[nt] = MFMA16(a, bx, acc[nt]);
        }
    }

    const int b = tok0 >> 11;
    const int n0b = tok0 & (N_DIM - 1);

    if (oy < 16) {
        // ---- Q or K: T[128][72] bf16 -> fragment-major QS/KS ----
        short* T = (short*)smem;
        const float* bias = isq ? bq : bk;
        const float scale = isq ? LOG2E : 1.f;
        float bvr[4];
#pragma unroll
        for (int r = 0; r < 4; ++r) bvr[r] = bias[o0 + wave * 16 + quad * 4 + r];
#pragma unroll
        for (int nt = 0; nt < 8; ++nt) {
            short4 pk;
            pk.x = f2bf((acc[nt][0] + bvr[0]) * scale);
            pk.y = f2bf((acc[nt][1] + bvr[1]) * scale);
            pk.z = f2bf((acc[nt][2] + bvr[2]) * scale);
            pk.w = f2bf((acc[nt][3] + bvr[3]) * scale);
            *(short4*)(T + (nt * 16 + lo) * 72 + wave * 16 + quad * 4) = pk;
        }
        __syncthreads();
        const int h = oyl;
        const int hb = h * 4 + b;
        short* dst = isq ? QS : KS;
#pragma unroll
        for (int s = 0; s < 4; ++s) {
            int cid = s * 256 + t;
            int ln = cid & 63, fi = cid >> 6;     // fi 0..15
            int ksd = fi & 1, rtl = fi >> 1;      // rtl 0..7
            bf16x8 v = *(const bf16x8*)(T + (rtl * 16 + (ln & 15)) * 72 + ksd * 32 + (ln >> 4) * 8);
            *(bf16x8*)(dst + (((size_t)(hb * 128 + (n0b >> 4) + rtl) * 2 + ksd) * 512 + ln * 8)) = v;
        }
    } else if (oy < 24) {
        // ---- V: T2[64][136] bf16 -> fragment-major VSu ----
        short* T2 = (short*)smem;
        float bvr[4];
#pragma unroll
        for (int r = 0; r < 4; ++r) bvr[r] = bv[o0 - 512 + wave * 16 + quad * 4 + r];
#pragma unroll
        for (int nt = 0; nt < 8; ++nt)
#pragma unroll
            for (int r = 0; r < 4; ++r) {
                int ol = wave * 16 + quad * 4 + r;
                T2[ol * 136 + nt * 16 + lo] = f2bf(acc[nt][r] + bvr[r]);
            }
        __syncthreads();
        const int h = oy - 16;
        const int hb = h * 4 + b;
#pragma unroll
        for (int s = 0; s < 4; ++s) {
            int cid = s * 256 + t;
            int ln = cid & 63, fi = cid >> 6;     // fi 0..15
            int dt = fi & 3, ksd = (fi >> 2) & 1, nbl = fi >> 3;
            int dl = dt * 16 + (ln & 15);
            int tkl = nbl * 64 + ksd * 32 + (ln >> 4) * 8;
            bf16x8 v = *(const bf16x8*)(T2 + dl * 136 + tkl);
            int nbg = (n0b >> 6) + nbl;
            *(bf16x8*)(VSu + ((size_t)(((hb * 32 + nbg) * 2 + ksd) * 4 + dt) * 64 + ln) * 8) = v;
        }
    } else {
        // ---- YP: T3[128][68] fp32 -> (b,n,d) float4 stores ----
        float* T3 = (float*)smem;
#pragma unroll
        for (int nt = 0; nt < 8; ++nt) {
            float4 f;
            f.x = acc[nt][0]; f.y = acc[nt][1]; f.z = acc[nt][2]; f.w = acc[nt][3];
            *(float4*)(T3 + (nt * 16 + lo) * 68 + wave * 16 + quad * 4) = f;
        }
        __syncthreads();
#pragma unroll
        for (int s = 0; s < 8; ++s) {
            int cid = s * 256 + t;
            int row = cid >> 4, c4 = (cid & 15) * 4;
            float4 f = *(const float4*)(T3 + row * 68 + c4);
            *(float4*)(Yo + ((size_t)(tok0 + row)) * 64 + c4) = f;
        }
    }
}

// ---------------------------------------------------------------------------
// rowsum partials over m-QUARTERS, 256-n tile per block (4 Q frag-pairs/wave).
// 1024 blocks. Quarters 0,1 -> RSp; 2,3 -> RSpW (dead-weight-region overlay).
// ---------------------------------------------------------------------------
__global__ __launch_bounds__(256, 4) void rowsum_mfma(
    const short* __restrict__ QS, const short* __restrict__ KS,
    float* __restrict__ RSp, float* __restrict__ RSpW)
{
    const int id = blockIdx.x;                     // 1024 blocks
    const int hb = ((id & 7) << 2) | ((id >> 3) & 3);   // h = id&7 -> XCD L2 locality
    const int zq = (id >> 5) & 3;                  // m-quarter
    const int n0 = (id >> 7) * 256;                // 8 n-tiles
    const int t = threadIdx.x, wave = t >> 6, lane = t & 63;
    const int lo = lane & 15, quad = lane >> 4;
    const f32x4 czero = {0.f, 0.f, 0.f, 0.f};

    bf16x8 a0[4], a1[4];
#pragma unroll
    for (int s = 0; s < 4; ++s) {
        int rt = (n0 >> 4) + s * 4 + wave;
        a0[s] = *(const bf16x8*)(QS + ((size_t)(hb * 128 + rt) * 2 + 0) * 512 + lane * 8);
        a1[s] = *(const bf16x8*)(QS + ((size_t)(hb * 128 + rt) * 2 + 1) * 512 + lane * 8);
    }

    float sm[4][4];
#pragma unroll
    for (int s = 0; s < 4; ++s)
#pragma unroll
        for (int r = 0; r < 4; ++r) sm[s][r] = 0.f;

    const short* kp = KS + ((size_t)(hb * 128) * 2) * 512 + lane * 8
                    + (size_t)zq * (N_DIM / 4 / 16) * 2 * 512;
    for (int m0 = 0; m0 < N_DIM / 4; m0 += 64) {
#pragma unroll
        for (int mt = 0; mt < 4; ++mt) {
            bf16x8 b0 = *(const bf16x8*)(kp + (mt * 2 + 0) * 512);
            bf16x8 b1 = *(const bf16x8*)(kp + (mt * 2 + 1) * 512);
#pragma unroll
            for (int s = 0; s < 4; ++s) {
                f32x4 c = MFMA16(a0[s], b0, czero);
                c = MFMA16(a1[s], b1, c);
#pragma unroll
                for (int r = 0; r < 4; ++r) sm[s][r] += fx2(c[r]);
            }
        }
        kp += 8 * 512;
    }

#pragma unroll
    for (int sft = 1; sft < 16; sft <<= 1)
#pragma unroll
        for (int s = 0; s < 4; ++s)
#pragma unroll
            for (int r = 0; r < 4; ++r) sm[s][r] += __shfl_xor(sm[s][r], sft);

    if (lo == 0) {
        float* dst = (zq < 2) ? (RSp  + (size_t)zq * HB * N_DIM)
                              : (RSpW + (size_t)(zq - 2) * HB * N_DIM);
#pragma unroll
        for (int s = 0; s < 4; ++s) {
            int row = n0 + s * 64 + wave * 16 + quad * 4;
#pragma unroll
            for (int r = 0; r < 4; ++r)
                dst[(size_t)hb * N_DIM + row + r] = sm[s][r];
        }
    }
}

// ---------------------------------------------------------------------------
// VS = VSu * 1/(sum of 4 rowsum partials) — same fragment-major layout in/out
// ---------------------------------------------------------------------------
__global__ __launch_bounds__(256) void v_scale(
    const short* __restrict__ VSu, const float* __restrict__ RSp,
    const float* __restrict__ RSpW, short* __restrict__ VS)
{
    int t = blockIdx.x * 256 + threadIdx.x;     // 0..524287
    int lane = t & 63, fidx = t >> 6;
    int ks = (fidx >> 2) & 1, nb = (fidx >> 3) & 31, hb = fidx >> 8;
    int n = nb * 64 + ks * 32 + (lane >> 4) * 8;
    bf16x8 v = *(const bf16x8*)(VSu + (size_t)t * 8);
    const float* r0 = RSp  + (size_t)hb * N_DIM + n;
    const float* r1 = r0 + (size_t)HB * N_DIM;
    const float* r2 = RSpW + (size_t)hb * N_DIM + n;
    const float* r3 = r2 + (size_t)HB * N_DIM;
    bf16x8 o;
#pragma unroll
    for (int j = 0; j < 8; ++j)
        o[j] = f2bf(bf2f(v[j]) / ((r0[j] + r1[j]) + (r2[j] + r3[j])));
    *(bf16x8*)(VS + (size_t)t * 8) = o;
}

// ---------------------------------------------------------------------------
// attnout: PA_z[hb,m,d] (bf16) = sum_{n in half z} exp2(Q'.K) Vsc[n,d]
// 256-m tile x n-half -> 512 blocks (2/CU; ~240 unified regs/wave caps at
// 2 waves/SIMD, so TLP can't hide latency — instead REMOVE the latency).
// V(i+1) is staged into a 2x8KB LDS double buffer via global_load_lds
// (wave-uniform dest + lane*16 == our fragment layout; zero VGPR cost).
// PV(i) reads V from LDS (~120cy pipelined) instead of point-of-use L2
// (~200-900cy), which was the exposed stall at 2 waves/SIMD. One
// __syncthreads per iter publishes the stage (its vmcnt drain retires loads
// issued ~1500cy earlier -> no stall). Q stays register-prefetched from L2.
// ---------------------------------------------------------------------------
__global__ __launch_bounds__(256, 2) void attnout_mfma(
    const short* __restrict__ QS, const short* __restrict__ KS,
    const short* __restrict__ VS,
    short* __restrict__ PA0, short* __restrict__ PA1)
{
    const int id = blockIdx.x;                     // 512 blocks
    const int hb = ((id & 7) << 2) | ((id >> 3) & 3);
    const int z = (id >> 5) & 1;
    const int m0 = (id >> 6) * 256;                // 8 m-tiles

    // [0,32KB): Pl (4 stripes x 8KB) / epilogue T (17.4KB)
    // [32KB,48KB): V stage double buffer (2 x 8KB)
    __shared__ __align__(16) char smem[49152];
    short* Pl = (short*)smem;
    char* Vst = smem + 32768;

    const int t = threadIdx.x, wave = t >> 6, lane = t & 63;
    const int lo = lane & 15, quad = lane >> 4;
    const f32x4 czero = {0.f, 0.f, 0.f, 0.f};

    // K fragments for the wave's 4 m-16-chunks (m-stripe s: rows s*64+wave*16+lo)
    bf16x8 bk0[4], bk1[4];
#pragma unroll
    for (int s = 0; s < 4; ++s) {
        int rt = (m0 >> 4) + s * 4 + wave;
        bk0[s] = *(const bf16x8*)(KS + ((size_t)(hb * 128 + rt) * 2 + 0) * 512 + lane * 8);
        bk1[s] = *(const bf16x8*)(KS + ((size_t)(hb * 128 + rt) * 2 + 1) * 512 + lane * 8);
    }

    f32x4 oacc[4][4];                 // [s][dt]
#pragma unroll
    for (int s = 0; s < 4; ++s)
#pragma unroll
        for (int dt = 0; dt < 4; ++dt) oacc[s][dt] = czero;

    const short* qp = QS + ((size_t)(hb * 128) * 2) * 512 + lane * 8
                    + (size_t)z * (N_DIM / 2 / 16) * 2 * 512;
    const short* vp0 = VS + ((size_t)(hb * 32) * 8) * 512 + lane * 8
                     + (size_t)z * (N_DIM / 2 / 64) * 8 * 512;
    short* prow = Pl + (wave * 16 + lo) * 64;      // + s*4096 selects P stripe
    const int lh = lo & 7;
    const int NIT = N_DIM / 2 / 64;   // 16

    f32x4 c[4][4];                    // E' [nt][s] for the "current" iteration

    // ---- stage V(0) into buffer 0 (2 frags per wave) ----
    {
        const short* src = vp0;
        gll16(src + (size_t)wave * 512,       Vst + wave * 1024, lane);
        gll16(src + (size_t)(wave + 4) * 512, Vst + (wave + 4) * 1024, lane);
    }

    // ---- prologue: QK(0) from L2 ----
    {
#pragma unroll
        for (int nt = 0; nt < 4; ++nt) {
            bf16x8 a0 = *(const bf16x8*)(qp + (nt * 2 + 0) * 512);
            bf16x8 a1 = *(const bf16x8*)(qp + (nt * 2 + 1) * 512);
#pragma unroll
            for (int s = 0; s < 4; ++s) {
                c[nt][s] = MFMA16(a0, bk0[s], czero);
                c[nt][s] = MFMA16(a1, bk1[s], c[nt][s]);
            }
        }
        qp += 8 * 512;
    }
    __syncthreads();                  // V(0) staged (vmcnt drained by barrier)

    for (int i = 0; i < NIT - 1; ++i) {
        // ---- stage V(i+1) into the other buffer (overlaps this iter's work) ----
        {
            const short* src = vp0 + ((size_t)(i + 1) * 8) * 512;
            char* dst = Vst + ((i + 1) & 1) * 8192;
            gll16(src + (size_t)wave * 512,       dst + wave * 1024, lane);
            gll16(src + (size_t)(wave + 4) * 512, dst + (wave + 4) * 1024, lane);
        }
        // ---- load Q fragments for iter i+1 (use separated by exp chain) ----
        bf16x8 a0[4], a1[4];
#pragma unroll
        for (int nt = 0; nt < 4; ++nt) {
            a0[nt] = *(const bf16x8*)(qp + (nt * 2 + 0) * 512);
            a1[nt] = *(const bf16x8*)(qp + (nt * 2 + 1) * 512);
        }
        // ---- expwrite(i): P = exp2(E') -> Pl stripes ----
#pragma unroll
        for (int nt = 0; nt < 4; ++nt)
#pragma unroll
            for (int s = 0; s < 4; ++s) {
                uint2 pk;
                pk.x = pk_bf16(fx2(c[nt][s][0]), fx2(c[nt][s][1]));
                pk.y = pk_bf16(fx2(c[nt][s][2]), fx2(c[nt][s][3]));
                int chunk = nt * 2 + (quad >> 1);
                *(uint2*)(prow + s * 4096 + (((chunk ^ lh) << 3) | ((quad & 1) << 2))) = pk;
            }
        // ---- QK-MFMA(i+1) (separates ds_write(i) from ds_read(i)) ----
        __builtin_amdgcn_s_setprio(1);
#pragma unroll
        for (int nt = 0; nt < 4; ++nt)
#pragma unroll
            for (int s = 0; s < 4; ++s) {
                c[nt][s] = MFMA16(a0[nt], bk0[s], czero);
                c[nt][s] = MFMA16(a1[nt], bk1[s], c[nt][s]);
            }
        __builtin_amdgcn_s_setprio(0);
        // ---- PV(i): P from Pl, V from LDS stage buffer i&1 ----
        {
            const char* vb = Vst + (i & 1) * 8192;
#pragma unroll
            for (int ks = 0; ks < 2; ++ks) {
                bf16x8 ap[4];
#pragma unroll
                for (int s = 0; s < 4; ++s)
                    ap[s] = *(const bf16x8*)(prow + s * 4096 + (((ks * 4 + quad) ^ lh) << 3));
#pragma unroll
                for (int dt = 0; dt < 4; ++dt) {
                    bf16x8 bv = *(const bf16x8*)(vb + (ks * 4 + dt) * 1024 + lane * 16);
#pragma unroll
                    for (int s = 0; s < 4; ++s)
                        oacc[s][dt] = MFMA16(ap[s], bv, oacc[s][dt]);
                }
            }
        }
        qp += 8 * 512;
        __syncthreads();              // publish V(i+1); Vbuf(i&1) reads done
    }

    // ---- tail: expwrite(NIT-1) + PV(NIT-1) ----
#pragma unroll
    for (int nt = 0; nt < 4; ++nt)
#pragma unroll
        for (int s = 0; s < 4; ++s) {
            uint2 pk;
            pk.x = pk_bf16(fx2(c[nt][s][0]), fx2(c[nt][s][1]));
            pk.y = pk_bf16(fx2(c[nt][s][2]), fx2(c[nt][s][3]));
            int chunk = nt * 2 + (quad >> 1);
            *(uint2*)(prow + s * 4096 + (((chunk ^ lh) << 3) | ((quad & 1) << 2))) = pk;
        }
    {
        const char* vb = Vst + ((NIT - 1) & 1) * 8192;
#pragma unroll
        for (int ks = 0; ks < 2; ++ks) {
            bf16x8 ap[4];
#pragma unroll
            for (int s = 0; s < 4; ++s)
                ap[s] = *(const bf16x8*)(prow + s * 4096 + (((ks * 4 + quad) ^ lh) << 3));
#pragma unroll
            for (int dt = 0; dt < 4; ++dt) {
                bf16x8 bv = *(const bf16x8*)(vb + (ks * 4 + dt) * 1024 + lane * 16);
#pragma unroll
                for (int s = 0; s < 4; ++s)
                    oacc[s][dt] = MFMA16(ap[s], bv, oacc[s][dt]);
            }
        }
    }

    // ---- epilogue: LDS transpose -> coalesced bf16 partial stores ----
    short* PA = z ? PA1 : PA0;
    float* T = (float*)smem;                      // [64][68]
#pragma unroll
    for (int s = 0; s < 4; ++s) {
        __syncthreads();                          // Pl / previous T reads done
#pragma unroll
        for (int dt = 0; dt < 4; ++dt)
#pragma unroll
            for (int r = 0; r < 4; ++r)
                T[(wave * 16 + quad * 4 + r) * 68 + dt * 16 + lo] = oacc[s][dt][r];
        __syncthreads();
#pragma unroll
        for (int it = 0; it < 2; ++it) {
            int idx = it * 256 + t;               // 0..511
            int rowl = idx >> 3, dg = (idx & 7) * 8;
            float4 f0 = *(const float4*)(T + rowl * 68 + dg);
            float4 f1 = *(const float4*)(T + rowl * 68 + dg + 4);
            uint4 o;
            o.x = pk_bf16(f0.x, f0.y);
            o.y = pk_bf16(f0.z, f0.w);
            o.z = pk_bf16(f1.x, f1.y);
            o.w = pk_bf16(f1.z, f1.w);
            int m = m0 + s * 64 + rowl;
            *(uint4*)(PA + ((size_t)(hb * N_DIM + m)) * 64 + dg) = o;
        }
    }
}

// ---------------------------------------------------------------------------
// out = g/(1+g) * (PA0 + PA1) + YP/(1+g)
// ---------------------------------------------------------------------------
__global__ __launch_bounds__(256) void combine_out(
    const short* __restrict__ PA0, const short* __restrict__ PA1,
    const float* __restrict__ YP, const float* __restrict__ gamma,
    float* __restrict__ out)
{
    size_t flat = ((size_t)blockIdx.x * 256 + threadIdx.x) * 8;
    int d  = (int)(flat & 63);
    int n  = (int)((flat >> 6) & (N_DIM - 1));
    int hb = (int)(flat >> 17);
    int h = hb >> 2, b = hb & 3;
    float g = gamma[h];
    float inv = 1.f / (1.f + g);
    float gi = g * inv;
    bf16x8 p0 = *(const bf16x8*)(PA0 + flat);
    bf16x8 p1 = *(const bf16x8*)(PA1 + flat);
    const float* yp = YP + ((size_t)b * N_DIM + n) * HD + d;
    float o[8];
#pragma unroll
    for (int j = 0; j < 8; ++j)
        o[j] = gi * (bf2f(p0[j]) + bf2f(p1[j])) + inv * yp[j];
    float4 o0 = {o[0], o[1], o[2], o[3]};
    float4 o1 = {o[4], o[5], o[6], o[7]};
    *(float4*)(out + flat) = o0;
    *(float4*)(out + flat + 4) = o1;
}

// ---------------------------------------------------------------------------
extern "C" void kernel_launch(void* const* d_in, const int* in_sizes, int n_in,
                              void* d_out, int out_size, void* d_ws, size_t ws_size,
                              hipStream_t stream) {
    const float* x     = (const float*)d_in[0];
    const float* y     = (const float*)d_in[1];
    const float* Wq    = (const float*)d_in[2];
    const float* bq    = (const float*)d_in[3];
    const float* Wk    = (const float*)d_in[4];
    const float* bk    = (const float*)d_in[5];
    const float* Wv    = (const float*)d_in[6];
    const float* bv    = (const float*)d_in[7];
    const float* Wp    = (const float*)d_in[8];
    const float* gamma = (const float*)d_in[9];
    float* out = (float*)d_out;

    const size_t XEL  = (size_t)B_DIM * C_DIM * N_DIM;  // 2,097,152
    const size_t QKV  = (size_t)HB * N_DIM * HD;        // 4,194,304

    short* XS  = (short*)d_ws;
    short* YS  = XS + XEL;
    short* WSx = YS + XEL;            // 512*256
    short* WSy = WSx + 512 * C_DIM;   // 1088*256
    short* QS  = WSy + 1088 * C_DIM;
    short* KS  = QS + QKV;
    short* VSu = KS + QKV;
    short* VS  = VSu + QKV;
    float* YPb = (float*)(VS + QKV);
    float* RSp = YPb + (size_t)B_DIM * N_DIM * HD;      // 2 * HB * N (quarters 0,1)
    // overlays (dead after their producers/consumers finish):
    short* PA0 = XS;                  // XS+YS region = exactly QKV shorts
    short* PA1 = VSu;                 // VSu dead after v_scale
    float* RSpW = (float*)WSx;        // quarters 2,3: weight region dead after proj_all
                                      // (needs 512 KB; WSx+WSy = 800 KB)

    dim3 blk(256);
    cast_all<<<dim3(N_DIM / 64, C_DIM / 64, 9), blk, 0, stream>>>(
        x, y, Wq, Wk, Wv, Wp, XS, YS, WSx, WSy);

    proj_all<<<dim3(NTOK / 128, 25), blk, 0, stream>>>(
        WSx, WSy, XS, YS, bq, bk, bv, QS, KS, VSu, YPb);

    rowsum_mfma<<<dim3(1024), blk, 0, stream>>>(QS, KS, RSp, RSpW);
    v_scale<<<dim3(2048), blk, 0, stream>>>(VSu, RSp, RSpW, VS);
    attnout_mfma<<<dim3(512), blk, 0, stream>>>(QS, KS, VS, PA0, PA1);
    combine_out<<<dim3(2048), blk, 0, stream>>>(PA0, PA1, YPb, gamma, out);
}